// Round 2
// baseline (1471.810 us; speedup 1.0000x reference)
//
#include <hip/hip_runtime.h>
#include <math.h>

// NeuralODE Tsit5, D=32, W=256, B=2048, T=32, NSUB=2 -> 372 sequential MLP evals.
// One launch: 128 blocks x 256 threads; block owns 16 batch rows end-to-end.
// Runtime dtype detect (f32 vs bf16 harness conversion) via ts bit pattern.
// MFMA in fp16: W1 slice (hi) persistent in VGPRs; activations hi/lo split
// (2-term for layer2, 3-term with weight-lo for layers 1/3) -> ~2^-11 worst
// relative GEMM error, state math in f32.

typedef unsigned short u16;
typedef __attribute__((ext_vector_type(8))) _Float16 half8;
typedef __attribute__((ext_vector_type(4))) float floatx4;

__device__ __forceinline__ float bf2f(u16 u) {
    return __uint_as_float(((unsigned int)u) << 16);
}
__device__ __forceinline__ u16 f2bf_rne(float f) {
    unsigned int u = __float_as_uint(f);
    unsigned int r = u + 0x7fffu + ((u >> 16) & 1u);
    return (u16)(r >> 16);
}
__device__ __forceinline__ float ldin(const void* p, int i, bool bf) {
    return bf ? bf2f(((const u16*)p)[i]) : ((const float*)p)[i];
}
__device__ __forceinline__ u16 hbits(_Float16 h) {
    union { _Float16 h; u16 u; } c; c.h = h; return c.u;
}
__device__ __forceinline__ float softplus_f(float x) {
    float e = exp2f(fabsf(x) * -1.442695040888963f);
    return fmaxf(x, 0.0f) + 0.6931471805599453f * log2f(1.0f + e);
}

__global__ __launch_bounds__(256, 1)
void node_tsit5_kernel(const void* __restrict__ tsv,
                       const void* __restrict__ y0v,
                       const void* __restrict__ W0v,
                       const void* __restrict__ b0v,
                       const void* __restrict__ W1v,
                       const void* __restrict__ b1v,
                       const void* __restrict__ W2v,
                       const void* __restrict__ b2v,
                       void* __restrict__ outv)
{
    const int tid  = threadIdx.x;
    const int wv   = tid >> 6;     // wave 0..3
    const int lane = tid & 63;
    const int q    = lane >> 4;    // quad 0..3
    const int nl   = lane & 15;
    const int row0 = (int)blockIdx.x << 4;

    // dtype: f32 ts[0]=0.0f -> u16[1]==0 ; bf16 ts[1]=0x3D04 != 0
    const bool bf = (((const u16*)tsv)[1] != 0);

    alignas(16) __shared__ u16 Xh[16][40],  Xl[16][40];
    alignas(16) __shared__ u16 H1h[16][264], H1l[16][264];
    alignas(16) __shared__ u16 H2h[16][264], H2l[16][264];
    __shared__ float Fp[4][16][33];

    // ---- persistent weight fragments (fp16). B-operand: lane holds W[n][k..k+7]
    half8 w1f[8][4];                       // W1 hi only: n=wv*64+nt*16+nl, k=kt*32+q*8
#pragma unroll
    for (int nt = 0; nt < 4; ++nt) {
        const int n = (wv << 6) + (nt << 4) + nl;
#pragma unroll
        for (int kt = 0; kt < 8; ++kt) {
            half8 v;
#pragma unroll
            for (int j = 0; j < 8; ++j)
                v[j] = (_Float16)ldin(W1v, n * 256 + kt * 32 + q * 8 + j, bf);
            w1f[kt][nt] = v;
        }
    }
    half8 w0h[4], w0l[4];                  // W0 hi+lo
#pragma unroll
    for (int nt = 0; nt < 4; ++nt) {
        const int n = (wv << 6) + (nt << 4) + nl;
        half8 vh, vl;
#pragma unroll
        for (int j = 0; j < 8; ++j) {
            float x = ldin(W0v, n * 32 + q * 8 + j, bf);
            _Float16 hh = (_Float16)x;
            vh[j] = hh;
            vl[j] = (_Float16)(x - (float)hh);
        }
        w0h[nt] = vh; w0l[nt] = vl;
    }
    half8 w2h[2][2], w2l[2][2];            // W2 hi+lo: wave wv covers k in [wv*64, wv*64+64)
#pragma unroll
    for (int kt = 0; kt < 2; ++kt)
#pragma unroll
        for (int nt = 0; nt < 2; ++nt) {
            half8 vh, vl;
#pragma unroll
            for (int j = 0; j < 8; ++j) {
                float x = ldin(W2v, (nt * 16 + nl) * 256 + (wv << 6) + kt * 32 + q * 8 + j, bf);
                _Float16 hh = (_Float16)x;
                vh[j] = hh;
                vl[j] = (_Float16)(x - (float)hh);
            }
            w2h[kt][nt] = vh; w2l[kt][nt] = vl;
        }

    float b0r[4], b1r[4], b2r[2];
#pragma unroll
    for (int nt = 0; nt < 4; ++nt) {
        b0r[nt] = ldin(b0v, (wv << 6) + (nt << 4) + nl, bf);
        b1r[nt] = ldin(b1v, (wv << 6) + (nt << 4) + nl, bf);
    }
#pragma unroll
    for (int nt = 0; nt < 2; ++nt) b2r[nt] = ldin(b2v, (nt << 4) + nl, bf);

    // ---- state in C/D layout (row=q*4+i, col=nt*16+nl), replicated per wave ----
    float y[2][4], k1[2][4], k2[2][4], k3[2][4], k4[2][4], k5[2][4], xs[2][4], fo[2][4];
#pragma unroll
    for (int nt = 0; nt < 2; ++nt)
#pragma unroll
        for (int i = 0; i < 4; ++i)
            y[nt][i] = ldin(y0v, (row0 + q * 4 + i) * 32 + (nt << 4) + nl, bf);

    auto feval = [&](const float (&x)[2][4], float (&f)[2][4]) {
        if (wv == 0) {
#pragma unroll
            for (int nt = 0; nt < 2; ++nt)
#pragma unroll
                for (int i = 0; i < 4; ++i) {
                    float v = x[nt][i];
                    _Float16 hh = (_Float16)v;
                    _Float16 ll = (_Float16)(v - (float)hh);
                    Xh[q * 4 + i][(nt << 4) + nl] = hbits(hh);
                    Xl[q * 4 + i][(nt << 4) + nl] = hbits(ll);
                }
        }
        __syncthreads();
        // layer 1: [16,32] @ W0[n][k], 3-term (AhWh + AlWh + AhWl)
        half8 xh = *(const half8*)&Xh[nl][q * 8];
        half8 xl = *(const half8*)&Xl[nl][q * 8];
        floatx4 acc[4];
#pragma unroll
        for (int nt = 0; nt < 4; ++nt) {
            acc[nt] = (floatx4){b0r[nt], b0r[nt], b0r[nt], b0r[nt]};
            acc[nt] = __builtin_amdgcn_mfma_f32_16x16x32_f16(xh, w0h[nt], acc[nt], 0, 0, 0);
            acc[nt] = __builtin_amdgcn_mfma_f32_16x16x32_f16(xl, w0h[nt], acc[nt], 0, 0, 0);
            acc[nt] = __builtin_amdgcn_mfma_f32_16x16x32_f16(xh, w0l[nt], acc[nt], 0, 0, 0);
        }
#pragma unroll
        for (int nt = 0; nt < 4; ++nt)
#pragma unroll
            for (int i = 0; i < 4; ++i) {
                float v = softplus_f(acc[nt][i]);
                _Float16 hh = (_Float16)v;
                _Float16 ll = (_Float16)(v - (float)hh);
                H1h[q * 4 + i][(wv << 6) + (nt << 4) + nl] = hbits(hh);
                H1l[q * 4 + i][(wv << 6) + (nt << 4) + nl] = hbits(ll);
            }
        __syncthreads();
        // layer 2: [16,256] @ W1[n][k], 2-term (W1 hi in VGPRs)
        floatx4 acc2[4];
#pragma unroll
        for (int nt = 0; nt < 4; ++nt)
            acc2[nt] = (floatx4){b1r[nt], b1r[nt], b1r[nt], b1r[nt]};
#pragma unroll
        for (int kt = 0; kt < 8; ++kt) {
            half8 ah = *(const half8*)&H1h[nl][kt * 32 + q * 8];
            half8 al = *(const half8*)&H1l[nl][kt * 32 + q * 8];
#pragma unroll
            for (int nt = 0; nt < 4; ++nt) {
                acc2[nt] = __builtin_amdgcn_mfma_f32_16x16x32_f16(ah, w1f[kt][nt], acc2[nt], 0, 0, 0);
                acc2[nt] = __builtin_amdgcn_mfma_f32_16x16x32_f16(al, w1f[kt][nt], acc2[nt], 0, 0, 0);
            }
        }
#pragma unroll
        for (int nt = 0; nt < 4; ++nt)
#pragma unroll
            for (int i = 0; i < 4; ++i) {
                float v = softplus_f(acc2[nt][i]);
                _Float16 hh = (_Float16)v;
                _Float16 ll = (_Float16)(v - (float)hh);
                H2h[q * 4 + i][(wv << 6) + (nt << 4) + nl] = hbits(hh);
                H2l[q * 4 + i][(wv << 6) + (nt << 4) + nl] = hbits(ll);
            }
        __syncthreads();
        // layer 3: K split across waves, 3-term, partials reduced via LDS
        floatx4 acc3[2];
        acc3[0] = (floatx4){0.f, 0.f, 0.f, 0.f};
        acc3[1] = (floatx4){0.f, 0.f, 0.f, 0.f};
#pragma unroll
        for (int kt = 0; kt < 2; ++kt) {
            half8 ah = *(const half8*)&H2h[nl][(wv << 6) + kt * 32 + q * 8];
            half8 al = *(const half8*)&H2l[nl][(wv << 6) + kt * 32 + q * 8];
#pragma unroll
            for (int nt = 0; nt < 2; ++nt) {
                acc3[nt] = __builtin_amdgcn_mfma_f32_16x16x32_f16(ah, w2h[kt][nt], acc3[nt], 0, 0, 0);
                acc3[nt] = __builtin_amdgcn_mfma_f32_16x16x32_f16(al, w2h[kt][nt], acc3[nt], 0, 0, 0);
                acc3[nt] = __builtin_amdgcn_mfma_f32_16x16x32_f16(ah, w2l[kt][nt], acc3[nt], 0, 0, 0);
            }
        }
#pragma unroll
        for (int nt = 0; nt < 2; ++nt)
#pragma unroll
            for (int i = 0; i < 4; ++i)
                Fp[wv][q * 4 + i][(nt << 4) + nl] = acc3[nt][i];
        __syncthreads();
#pragma unroll
        for (int nt = 0; nt < 2; ++nt)
#pragma unroll
            for (int i = 0; i < 4; ++i)
                f[nt][i] = b2r[nt]
                         + ((Fp[0][q * 4 + i][(nt << 4) + nl] + Fp[1][q * 4 + i][(nt << 4) + nl])
                          + (Fp[2][q * 4 + i][(nt << 4) + nl] + Fp[3][q * 4 + i][(nt << 4) + nl]));
    };

    u16*   o16 = (u16*)outv;
    float* o32 = (float*)outv;
    auto store_y = [&](int t) {
        if (wv < 2) {
#pragma unroll
            for (int i = 0; i < 4; ++i) {
                size_t idx = (size_t)(t * 2048 + row0 + q * 4 + i) * 32 + (wv << 4) + nl;
                float v = y[wv][i];
                if (bf) o16[idx] = f2bf_rne(v);
                else    o32[idx] = v;
            }
        }
    };

    store_y(0);

    const float A21 = 0.161f;
    const float A31 = -0.008480655492356989f, A32 = 0.335480655492357f;
    const float A41 = 2.8971530571054935f, A42 = -6.359448489975075f, A43 = 4.3622954328695815f;
    const float A51 = 5.325864828439257f, A52 = -11.748883564062828f, A53 = 7.4955393428898365f, A54 = -0.09249506636175525f;
    const float A61 = 5.86145544294642f, A62 = -12.92096931784711f, A63 = 8.159367898576159f, A64 = -0.071584973281401f, A65 = -0.028269050394068383f;
    const float B1 = 0.09646076681806523f, B2 = 0.01f, B3 = 0.4798896504144996f;
    const float B4 = 1.379008574103742f, B5 = -3.290069515436081f, B6 = 2.324710524099774f;

    float tprev = ldin(tsv, 0, bf);
#pragma unroll 1
    for (int t = 1; t < 32; ++t) {
        float tcur = ldin(tsv, t, bf);
        const float h = (tcur - tprev) * 0.5f;   // /NSUB
        tprev = tcur;
#pragma unroll 1
        for (int s = 0; s < 2; ++s) {
#pragma unroll
            for (int nt = 0; nt < 2; ++nt)
#pragma unroll
                for (int i = 0; i < 4; ++i) xs[nt][i] = y[nt][i];
#pragma unroll 1
            for (int st = 0; st < 6; ++st) {
                feval(xs, fo);
                if (st == 0) {
#pragma unroll
                    for (int nt = 0; nt < 2; ++nt)
#pragma unroll
                        for (int i = 0; i < 4; ++i) {
                            k1[nt][i] = fo[nt][i];
                            xs[nt][i] = fmaf(h, A21 * fo[nt][i], y[nt][i]);
                        }
                } else if (st == 1) {
#pragma unroll
                    for (int nt = 0; nt < 2; ++nt)
#pragma unroll
                        for (int i = 0; i < 4; ++i) {
                            k2[nt][i] = fo[nt][i];
                            float sum = fmaf(A32, fo[nt][i], A31 * k1[nt][i]);
                            xs[nt][i] = fmaf(h, sum, y[nt][i]);
                        }
                } else if (st == 2) {
#pragma unroll
                    for (int nt = 0; nt < 2; ++nt)
#pragma unroll
                        for (int i = 0; i < 4; ++i) {
                            k3[nt][i] = fo[nt][i];
                            float sum = fmaf(A43, fo[nt][i], fmaf(A42, k2[nt][i], A41 * k1[nt][i]));
                            xs[nt][i] = fmaf(h, sum, y[nt][i]);
                        }
                } else if (st == 3) {
#pragma unroll
                    for (int nt = 0; nt < 2; ++nt)
#pragma unroll
                        for (int i = 0; i < 4; ++i) {
                            k4[nt][i] = fo[nt][i];
                            float sum = fmaf(A54, fo[nt][i],
                                        fmaf(A53, k3[nt][i], fmaf(A52, k2[nt][i], A51 * k1[nt][i])));
                            xs[nt][i] = fmaf(h, sum, y[nt][i]);
                        }
                } else if (st == 4) {
#pragma unroll
                    for (int nt = 0; nt < 2; ++nt)
#pragma unroll
                        for (int i = 0; i < 4; ++i) {
                            k5[nt][i] = fo[nt][i];
                            float sum = fmaf(A65, fo[nt][i],
                                        fmaf(A64, k4[nt][i],
                                        fmaf(A63, k3[nt][i], fmaf(A62, k2[nt][i], A61 * k1[nt][i]))));
                            xs[nt][i] = fmaf(h, sum, y[nt][i]);
                        }
                } else {
#pragma unroll
                    for (int nt = 0; nt < 2; ++nt)
#pragma unroll
                        for (int i = 0; i < 4; ++i) {
                            float sum = fmaf(B6, fo[nt][i],
                                        fmaf(B5, k5[nt][i],
                                        fmaf(B4, k4[nt][i],
                                        fmaf(B3, k3[nt][i], fmaf(B2, k2[nt][i], B1 * k1[nt][i])))));
                            y[nt][i] = fmaf(h, sum, y[nt][i]);
                        }
                }
            }
        }
        store_y(t);
    }
}

extern "C" void kernel_launch(void* const* d_in, const int* in_sizes, int n_in,
                              void* d_out, int out_size, void* d_ws, size_t ws_size,
                              hipStream_t stream) {
    (void)in_sizes; (void)n_in; (void)d_ws; (void)ws_size; (void)out_size;
    node_tsit5_kernel<<<dim3(128), dim3(256), 0, stream>>>(
        d_in[0], d_in[1], d_in[2], d_in[3], d_in[4], d_in[5], d_in[6], d_in[7], d_out);
}

// Round 3
// 794.434 us; speedup vs baseline: 1.8527x; 1.8527x over previous
//
#include <hip/hip_runtime.h>
#include <math.h>

// NeuralODE Tsit5: D=32, W=256, B=2048, T=32, NSUB=2 -> 372 sequential MLP evals.
// 128 blocks x 512 threads (8 waves, 2/SIMD). Block owns 16 batch rows end-to-end.
// N=256 split across 8 waves (32 cols each); ODE state distributed: wave w owns
// output element (nt,i)=(w>>2,w&3). fp16 MFMA: L1 3-term, L2 1-term (W1h in
// VGPRs), L3 2-term (W2 hi+lo), K-split over waves 0-3 + LDS reduce.
// Runtime dtype detect (f32 vs bf16) via ts[1] bits.

typedef unsigned short u16;
typedef __attribute__((ext_vector_type(8))) _Float16 half8;
typedef __attribute__((ext_vector_type(4))) float floatx4;

__device__ __forceinline__ float bf2f(u16 u) {
    return __uint_as_float(((unsigned int)u) << 16);
}
__device__ __forceinline__ u16 f2bf_rne(float f) {
    unsigned int u = __float_as_uint(f);
    unsigned int r = u + 0x7fffu + ((u >> 16) & 1u);
    return (u16)(r >> 16);
}
__device__ __forceinline__ float ldin(const void* p, int i, bool bf) {
    return bf ? bf2f(((const u16*)p)[i]) : ((const float*)p)[i];
}
__device__ __forceinline__ u16 hbits(_Float16 h) {
    union { _Float16 h; u16 u; } c; c.h = h; return c.u;
}
__device__ __forceinline__ float softplus_f(float x) {
    float e = exp2f(fabsf(x) * -1.442695040888963f);
    return fmaxf(x, 0.0f) + 0.6931471805599453f * log2f(1.0f + e);
}

__global__ __launch_bounds__(512, 2)
void node_tsit5_kernel(const void* __restrict__ tsv,
                       const void* __restrict__ y0v,
                       const void* __restrict__ W0v,
                       const void* __restrict__ b0v,
                       const void* __restrict__ W1v,
                       const void* __restrict__ b1v,
                       const void* __restrict__ W2v,
                       const void* __restrict__ b2v,
                       void* __restrict__ outv)
{
    const int tid  = threadIdx.x;
    const int wv   = tid >> 6;       // 0..7
    const int lane = tid & 63;
    const int q    = lane >> 4;      // quad 0..3
    const int nl   = lane & 15;
    const int row0 = (int)blockIdx.x << 4;
    const int nt_s = wv >> 2;        // state ownership: col tile
    const int i_s  = wv & 3;         // state ownership: acc reg index
    const int c0   = wv << 5;        // this wave's 32-col slice of N=256

    const bool bf = (((const u16*)tsv)[1] != 0);

    // strides: 264 u16 = 528 B (16B-aligned; b16 writes 4-way - floor for aligned rows)
    // Fp stride 36 dw -> bank = nl + 16*(q&1): 2-way (free)
    alignas(16) __shared__ u16 Xh[16][40], Xl[16][40];
    alignas(16) __shared__ u16 H1h[16][264], H2h[16][264];
    __shared__ float Fp[4][16][36];

    // ---- persistent fp16 weight fragments (B-operand: lane holds W[n][k..k+7]) ----
    half8 w1f[8][2];                 // W1 hi: n = c0 + nt*16 + nl, k = kt*32 + q*8
#pragma unroll
    for (int nt = 0; nt < 2; ++nt) {
        const int n = c0 + (nt << 4) + nl;
#pragma unroll
        for (int kt = 0; kt < 8; ++kt) {
            half8 v;
#pragma unroll
            for (int j = 0; j < 8; ++j)
                v[j] = (_Float16)ldin(W1v, n * 256 + kt * 32 + q * 8 + j, bf);
            w1f[kt][nt] = v;
        }
    }
    half8 w0h[2], w0l[2];            // W0 hi+lo
#pragma unroll
    for (int nt = 0; nt < 2; ++nt) {
        const int n = c0 + (nt << 4) + nl;
        half8 vh, vl;
#pragma unroll
        for (int j = 0; j < 8; ++j) {
            float x = ldin(W0v, n * 32 + q * 8 + j, bf);
            _Float16 hh = (_Float16)x;
            vh[j] = hh;
            vl[j] = (_Float16)(x - (float)hh);
        }
        w0h[nt] = vh; w0l[nt] = vl;
    }
    half8 w2h[2][2], w2l[2][2];      // waves 0..3: K-slice [wv*64, wv*64+64)
    if (wv < 4) {
        const int k0 = wv << 6;
#pragma unroll
        for (int kt = 0; kt < 2; ++kt)
#pragma unroll
            for (int nt = 0; nt < 2; ++nt) {
                half8 vh, vl;
#pragma unroll
                for (int j = 0; j < 8; ++j) {
                    float x = ldin(W2v, (nt * 16 + nl) * 256 + k0 + kt * 32 + q * 8 + j, bf);
                    _Float16 hh = (_Float16)x;
                    vh[j] = hh;
                    vl[j] = (_Float16)(x - (float)hh);
                }
                w2h[kt][nt] = vh; w2l[kt][nt] = vl;
            }
    }

    float b0r[2], b1r[2];
#pragma unroll
    for (int nt = 0; nt < 2; ++nt) {
        b0r[nt] = ldin(b0v, c0 + (nt << 4) + nl, bf);
        b1r[nt] = ldin(b1v, c0 + (nt << 4) + nl, bf);
    }
    const float b2w = ldin(b2v, (nt_s << 4) + nl, bf);

    // ---- distributed state: this wave's lane (q,nl) owns element
    //      (row = q*4 + i_s, col = nt_s*16 + nl) ----
    float yw = ldin(y0v, (row0 + q * 4 + i_s) * 32 + (nt_s << 4) + nl, bf);
    float kk0, kk1, kk2, kk3, kk4, xsw, fow;

    u16*   o16 = (u16*)outv;
    float* o32 = (float*)outv;
    auto store_y = [&](int t) {
        size_t idx = (size_t)(t * 2048 + row0 + q * 4 + i_s) * 32 + (nt_s << 4) + nl;
        if (bf) o16[idx] = f2bf_rne(yw);
        else    o32[idx] = yw;
    };

    auto feval = [&](float xin) -> float {
        // stage x (hi/lo split), each wave writes its own state element
        {
            _Float16 hh = (_Float16)xin;
            _Float16 ll = (_Float16)(xin - (float)hh);
            Xh[q * 4 + i_s][(nt_s << 4) + nl] = hbits(hh);
            Xl[q * 4 + i_s][(nt_s << 4) + nl] = hbits(ll);
        }
        __syncthreads();                                   // barX
        // layer 1: [16,32] @ W0, 3-term
        half8 xh = *(const half8*)&Xh[nl][q * 8];
        half8 xl = *(const half8*)&Xl[nl][q * 8];
        floatx4 acc[2];
#pragma unroll
        for (int nt = 0; nt < 2; ++nt) {
            acc[nt] = (floatx4){b0r[nt], b0r[nt], b0r[nt], b0r[nt]};
            acc[nt] = __builtin_amdgcn_mfma_f32_16x16x32_f16(xh, w0h[nt], acc[nt], 0, 0, 0);
            acc[nt] = __builtin_amdgcn_mfma_f32_16x16x32_f16(xl, w0h[nt], acc[nt], 0, 0, 0);
            acc[nt] = __builtin_amdgcn_mfma_f32_16x16x32_f16(xh, w0l[nt], acc[nt], 0, 0, 0);
        }
#pragma unroll
        for (int nt = 0; nt < 2; ++nt)
#pragma unroll
            for (int i = 0; i < 4; ++i)
                H1h[q * 4 + i][c0 + (nt << 4) + nl] = hbits((_Float16)softplus_f(acc[nt][i]));
        __syncthreads();                                   // barH1
        // layer 2: [16,256] @ W1h (VGPR-resident), 1-term
        floatx4 acc2[2];
#pragma unroll
        for (int nt = 0; nt < 2; ++nt)
            acc2[nt] = (floatx4){b1r[nt], b1r[nt], b1r[nt], b1r[nt]};
#pragma unroll
        for (int kt = 0; kt < 8; ++kt) {
            half8 ah = *(const half8*)&H1h[nl][kt * 32 + q * 8];
#pragma unroll
            for (int nt = 0; nt < 2; ++nt)
                acc2[nt] = __builtin_amdgcn_mfma_f32_16x16x32_f16(ah, w1f[kt][nt], acc2[nt], 0, 0, 0);
        }
#pragma unroll
        for (int nt = 0; nt < 2; ++nt)
#pragma unroll
            for (int i = 0; i < 4; ++i)
                H2h[q * 4 + i][c0 + (nt << 4) + nl] = hbits((_Float16)softplus_f(acc2[nt][i]));
        __syncthreads();                                   // barH2
        // layer 3: waves 0-3, K=64 slice each, 2-term (W2 hi+lo)
        if (wv < 4) {
            floatx4 acc3[2];
            acc3[0] = (floatx4){0.f, 0.f, 0.f, 0.f};
            acc3[1] = (floatx4){0.f, 0.f, 0.f, 0.f};
#pragma unroll
            for (int kt = 0; kt < 2; ++kt) {
                half8 ah = *(const half8*)&H2h[nl][(wv << 6) + kt * 32 + q * 8];
#pragma unroll
                for (int nt = 0; nt < 2; ++nt) {
                    acc3[nt] = __builtin_amdgcn_mfma_f32_16x16x32_f16(ah, w2h[kt][nt], acc3[nt], 0, 0, 0);
                    acc3[nt] = __builtin_amdgcn_mfma_f32_16x16x32_f16(ah, w2l[kt][nt], acc3[nt], 0, 0, 0);
                }
            }
#pragma unroll
            for (int nt = 0; nt < 2; ++nt)
#pragma unroll
                for (int i = 0; i < 4; ++i)
                    Fp[wv][q * 4 + i][(nt << 4) + nl] = acc3[nt][i];
        }
        __syncthreads();                                   // barFp
        const int r = q * 4 + i_s, c = (nt_s << 4) + nl;
        return b2w + ((Fp[0][r][c] + Fp[1][r][c]) + (Fp[2][r][c] + Fp[3][r][c]));
    };

    store_y(0);

    const float A21 = 0.161f;
    const float A31 = -0.008480655492356989f, A32 = 0.335480655492357f;
    const float A41 = 2.8971530571054935f, A42 = -6.359448489975075f, A43 = 4.3622954328695815f;
    const float A51 = 5.325864828439257f, A52 = -11.748883564062828f, A53 = 7.4955393428898365f, A54 = -0.09249506636175525f;
    const float A61 = 5.86145544294642f, A62 = -12.92096931784711f, A63 = 8.159367898576159f, A64 = -0.071584973281401f, A65 = -0.028269050394068383f;
    const float B1 = 0.09646076681806523f, B2 = 0.01f, B3 = 0.4798896504144996f;
    const float B4 = 1.379008574103742f, B5 = -3.290069515436081f, B6 = 2.324710524099774f;

    float tprev = ldin(tsv, 0, bf);
#pragma unroll 1
    for (int t = 1; t < 32; ++t) {
        float tcur = ldin(tsv, t, bf);
        const float h = (tcur - tprev) * 0.5f;   // /NSUB
        tprev = tcur;
#pragma unroll 1
        for (int s = 0; s < 2; ++s) {
            xsw = yw;
#pragma unroll 1
            for (int st = 0; st < 6; ++st) {
                fow = feval(xsw);
                if (st == 0) {
                    kk0 = fow;
                    xsw = fmaf(h, A21 * fow, yw);
                } else if (st == 1) {
                    kk1 = fow;
                    xsw = fmaf(h, fmaf(A32, fow, A31 * kk0), yw);
                } else if (st == 2) {
                    kk2 = fow;
                    xsw = fmaf(h, fmaf(A43, fow, fmaf(A42, kk1, A41 * kk0)), yw);
                } else if (st == 3) {
                    kk3 = fow;
                    xsw = fmaf(h, fmaf(A54, fow,
                               fmaf(A53, kk2, fmaf(A52, kk1, A51 * kk0))), yw);
                } else if (st == 4) {
                    kk4 = fow;
                    xsw = fmaf(h, fmaf(A65, fow,
                               fmaf(A64, kk3, fmaf(A63, kk2,
                               fmaf(A62, kk1, A61 * kk0)))), yw);
                } else {
                    yw = fmaf(h, fmaf(B6, fow,
                              fmaf(B5, kk4, fmaf(B4, kk3,
                              fmaf(B3, kk2, fmaf(B2, kk1, B1 * kk0))))), yw);
                }
            }
        }
        store_y(t);
    }
}

extern "C" void kernel_launch(void* const* d_in, const int* in_sizes, int n_in,
                              void* d_out, int out_size, void* d_ws, size_t ws_size,
                              hipStream_t stream) {
    (void)in_sizes; (void)n_in; (void)d_ws; (void)ws_size; (void)out_size;
    node_tsit5_kernel<<<dim3(128), dim3(512), 0, stream>>>(
        d_in[0], d_in[1], d_in[2], d_in[3], d_in[4], d_in[5], d_in[6], d_in[7], d_out);
}